// Round 10
// baseline (187.422 us; speedup 1.0000x reference)
//
#include <hip/hip_runtime.h>
#include <hip/hip_bf16.h>

// Problem constants
#define Bn 2
#define Qn 21760
#define BQ 43520        // Bn*Qn
#define HWSUM 21760     // 128^2 + 64^2 + 32^2 + 16^2

typedef __attribute__((ext_vector_type(8))) short bf16x8;
typedef __attribute__((ext_vector_type(4))) float f32x4;
typedef __attribute__((ext_vector_type(2))) float f32x2;

static __device__ __forceinline__ unsigned short f2bf(float f) {
    __hip_bfloat16 h = __float2bfloat16(f);
    return __builtin_bit_cast(unsigned short, h);
}
static __device__ __forceinline__ float bf2f(unsigned short u) {
    return __uint_as_float(((unsigned)u) << 16);
}
static __device__ __forceinline__ void async16(const void* g, void* l) {
    __builtin_amdgcn_global_load_lds(
        (const __attribute__((address_space(1))) unsigned int*)g,
        (__attribute__((address_space(3))) unsigned int*)l, 16, 0, 0);
}
static __device__ __forceinline__ f32x2 up2(unsigned u) {
    uint2 t = make_uint2(u << 16, u & 0xffff0000u);
    return __builtin_bit_cast(f32x2, t);
}
static __device__ __forceinline__ f32x2 fma2(float s, f32x2 v, f32x2 a) {
    f32x2 sv = {s, s};
    return __builtin_elementwise_fma(sv, v, a);
}

#define PKPAIR(F0, F1, HP, LP) { \
        unsigned short h0_ = f2bf(F0), h1_ = f2bf(F1); \
        HP = (unsigned)h0_ | ((unsigned)h1_ << 16); \
        LP = (unsigned)f2bf((F0) - bf2f(h0_)) | ((unsigned)f2bf((F1) - bf2f(h1_)) << 16); }

static __device__ __forceinline__ int bin_of(const float* refp, int q) {
    float rx = refp[(size_t)q * 2], ry = refp[(size_t)q * 2 + 1];
    int cx = (int)(rx * 16.0f); cx = min(max(cx, 0), 15);
    int cy = (int)(ry * 16.0f); cy = min(max(cy, 0), 15);
    int m = 0;
#pragma unroll
    for (int i = 0; i < 4; ++i)
        m |= (((cx >> i) & 1) << (2 * i)) | (((cy >> i) & 1) << (2 * i + 1));
    return ((q >= Qn) ? 256 : 0) + m;
}

// ---------------------------------------------------------------------------
// Prep: weight split+transpose (blocks 0..159) + query histogram (160..329).
// hist zeroed by hipMemsetAsync before this launch.
// ---------------------------------------------------------------------------
__global__ __launch_bounds__(256) void prep_kernel(
    const float* __restrict__ Woff, const float* __restrict__ Wattn,
    const float* __restrict__ Wout,
    unsigned short* __restrict__ Wcat, unsigned short* __restrict__ Wlo,
    unsigned short* __restrict__ woutT,
    const float* __restrict__ refp, int* hist)
{
    int bid = blockIdx.x;
    if (bid >= 160) {                           // histogram
        int gid = (bid - 160) * 256 + threadIdx.x;
        if (gid < BQ) atomicAdd(&hist[bin_of(refp, gid)], 1);
        return;
    }
    __shared__ float tile[32][33];
    int bx = bid % 20, k8 = bid / 20;
    const float* W;
    unsigned short* bthi;
    unsigned short* btlo = nullptr;
    int N, dolo, nb;
    if (bx < 8)       { W = Woff;  bthi = Wcat;             btlo = Wlo; N = 256; dolo = 1; nb = bx; }
    else if (bx < 12) { W = Wattn; bthi = Wcat + 256 * 256; N = 128; dolo = 0; nb = bx - 8; }
    else              { W = Wout;  bthi = woutT;            N = 256; dolo = 0; nb = bx - 12; }
    int n0 = nb * 32, k0 = k8 * 32;
    int tx = threadIdx.x & 31, ty = threadIdx.x >> 5;
#pragma unroll
    for (int r = ty; r < 32; r += 8)
        tile[r][tx] = W[(size_t)(k0 + r) * N + n0 + tx];
    __syncthreads();
#pragma unroll
    for (int r = ty; r < 32; r += 8) {
        float v = tile[tx][r];
        unsigned short h = f2bf(v);
        bthi[(size_t)(n0 + r) * 256 + k0 + tx] = h;
        if (dolo) btlo[(size_t)(n0 + r) * 256 + k0 + tx] = f2bf(v - bf2f(h));
    }
}

// ---------------------------------------------------------------------------
// MEGA kernel: three independent jobs co-resident on the GPU so the MFMA-bound
// qproj overlaps the HBM-bound transpose (different pipes).
//   blocks [0,680)      : qproj  (offsets split-precision+tanh, attn+softmax)
//   blocks [680,850)    : scatter (with redundant in-block 512-bin scan)
//   blocks [850,11730)  : feat transpose fp32 (B,C,H,W) -> bf16 (B,8h,pos,32c)
// One 48KB smem union; __launch_bounds__(256,3) = 3 blocks/CU.
// ---------------------------------------------------------------------------
__global__ __launch_bounds__(256, 3) void mega_kernel(
    const float* __restrict__ A,
    const unsigned short* __restrict__ Wcat, const unsigned short* __restrict__ Wlo,
    const float* __restrict__ b_off, const float* __restrict__ b_attn,
    float* __restrict__ offs, float* __restrict__ attn_out,
    const float* __restrict__ f0, const float* __restrict__ f1,
    const float* __restrict__ f2, const float* __restrict__ f3,
    unsigned short* __restrict__ ft,
    const float* __restrict__ refp, const int* __restrict__ hist,
    int* cnt, int* order)
{
    __shared__ __align__(16) char smem[49152];
    int bid = blockIdx.x;
    int tid = threadIdx.x;

    if (bid < 680) {
        // ---------------- qproj ----------------
        unsigned short* Ah = (unsigned short*)smem;            //  4096 B
        unsigned short* Al = (unsigned short*)(smem + 4096);   //  4096 B
        unsigned short* Bh = (unsigned short*)(smem + 8192);   // 24576 B
        unsigned short* Bl = (unsigned short*)(smem + 32768);  // 16384 B
        int m0 = bid * 64;
        int wave = tid >> 6, lane = tid & 63;
        int wr = wave >> 1, wc = wave & 1;
        int lr = lane & 15, kb = (lane >> 4) * 8;
        int srow = tid >> 2, sseg = (tid & 3) * 8;
        const float* Ag = A + (size_t)(m0 + srow) * 256 + sseg;

        f32x4 acc[2][12] = {};

        for (int kt = 0; kt < 256; kt += 32) {
#pragma unroll
            for (int p = 0; p < 6; ++p) {
                int tile = tid + p * 256;
                int row = tile >> 2, seg = tile & 3;
                async16(Wcat + (size_t)row * 256 + kt + seg * 8, &Bh[tile * 8]);
            }
#pragma unroll
            for (int p = 0; p < 4; ++p) {
                int tile = tid + p * 256;
                int row = tile >> 2, seg = tile & 3;
                async16(Wlo + (size_t)row * 256 + kt + seg * 8, &Bl[tile * 8]);
            }
            float4 q0 = *(const float4*)(Ag + kt);
            float4 q1 = *(const float4*)(Ag + kt + 4);
            uint4 HP, LP;
            PKPAIR(q0.x, q0.y, HP.x, LP.x); PKPAIR(q0.z, q0.w, HP.y, LP.y);
            PKPAIR(q1.x, q1.y, HP.z, LP.z); PKPAIR(q1.z, q1.w, HP.w, LP.w);
            *(uint4*)&Ah[srow * 32 + sseg] = HP;
            *(uint4*)&Al[srow * 32 + sseg] = LP;
            __syncthreads();

            bf16x8 ah[2], al[2];
#pragma unroll
            for (int i = 0; i < 2; ++i) {
                ah[i] = *(const bf16x8*)&Ah[(wr * 32 + i * 16 + lr) * 32 + kb];
                al[i] = *(const bf16x8*)&Al[(wr * 32 + i * 16 + lr) * 32 + kb];
            }
#pragma unroll
            for (int j = 0; j < 12; ++j) {
                int c16 = j * 2 + wc;
                bf16x8 bh = *(const bf16x8*)&Bh[(c16 * 16 + lr) * 32 + kb];
                if (j < 8) {
                    bf16x8 bl = *(const bf16x8*)&Bl[(c16 * 16 + lr) * 32 + kb];
#pragma unroll
                    for (int i = 0; i < 2; ++i) {
                        acc[i][j] = __builtin_amdgcn_mfma_f32_16x16x32_bf16(ah[i], bh, acc[i][j], 0, 0, 0);
                        acc[i][j] = __builtin_amdgcn_mfma_f32_16x16x32_bf16(al[i], bh, acc[i][j], 0, 0, 0);
                        acc[i][j] = __builtin_amdgcn_mfma_f32_16x16x32_bf16(ah[i], bl, acc[i][j], 0, 0, 0);
                    }
                } else {
#pragma unroll
                    for (int i = 0; i < 2; ++i)
                        acc[i][j] = __builtin_amdgcn_mfma_f32_16x16x32_bf16(ah[i], bh, acc[i][j], 0, 0, 0);
                }
            }
            __syncthreads();
        }

        int crow = (lane >> 4) * 4;
#pragma unroll
        for (int j = 0; j < 12; ++j) {
            int c16 = j * 2 + wc;
            if (j < 8) {
                int col = c16 * 16 + lr;
                float bv = b_off[col];
#pragma unroll
                for (int i = 0; i < 2; ++i) {
                    int grow = m0 + wr * 32 + i * 16 + crow;
#pragma unroll
                    for (int r = 0; r < 4; ++r)
                        offs[(size_t)(grow + r) * 256 + col] = tanhf(acc[i][j][r] + bv);
                }
            } else {
                int col = (c16 - 16) * 16 + lr;
                float bv = b_attn[col];
#pragma unroll
                for (int i = 0; i < 2; ++i) {
                    int grow = m0 + wr * 32 + i * 16 + crow;
#pragma unroll
                    for (int r = 0; r < 4; ++r) {
                        float v = acc[i][j][r] + bv;
                        float mx = v;
                        mx = fmaxf(mx, __shfl_xor(mx, 1));
                        mx = fmaxf(mx, __shfl_xor(mx, 2));
                        mx = fmaxf(mx, __shfl_xor(mx, 4));
                        mx = fmaxf(mx, __shfl_xor(mx, 8));
                        float e = expf(v - mx);
                        float s = e;
                        s += __shfl_xor(s, 1);
                        s += __shfl_xor(s, 2);
                        s += __shfl_xor(s, 4);
                        s += __shfl_xor(s, 8);
                        attn_out[(size_t)(grow + r) * 128 + col] = e / s;
                    }
                }
            }
        }
    } else if (bid < 850) {
        // ---------------- scatter with in-block scan ----------------
        int* s = (int*)smem;
        int t = tid;
        int h0 = hist[t], h1 = hist[t + 256];
        s[t] = h0; s[t + 256] = h1;
        __syncthreads();
        for (int d = 1; d < 512; d <<= 1) {
            int v0 = (t >= d) ? s[t - d] : 0;
            int v1 = (t + 256 >= d) ? s[t + 256 - d] : 0;
            __syncthreads();
            s[t] += v0; s[t + 256] += v1;
            __syncthreads();
        }
        int e0 = s[t] - h0, e1 = s[t + 256] - h1;   // exclusive prefix
        __syncthreads();
        s[t] = e0; s[t + 256] = e1;
        __syncthreads();
        int q = (bid - 680) * 256 + t;              // 170*256 == BQ exactly
        int b = bin_of(refp, q);
        int idx = s[b] + atomicAdd(&cnt[b], 1);
        order[idx] = q;
    } else {
        // ---------------- feat transpose ----------------
        float (*tile)[33] = (float(*)[33])smem;
        int idx = bid - 850;
        int bx = idx % 1360;
        int h = idx / 1360;
        int b = bx / 680;
        int pos0 = (bx - b * 680) * 32;
        int c0 = h * 32;
        int lvl = (pos0 >= 21504) ? 3 : (pos0 >= 20480) ? 2 : (pos0 >= 16384) ? 1 : 0;
        int HW = 16384 >> (2 * lvl);
        int base = (lvl == 0) ? 0 : (lvl == 1) ? 16384 : (lvl == 2) ? 20480 : 21504;
        const float* f = (lvl == 0) ? f0 : (lvl == 1) ? f1 : (lvl == 2) ? f2 : f3;
        const float* src = f + (size_t)(b * 256 + c0) * HW + (pos0 - base);
        int tx = tid & 31, ty = tid >> 5;
#pragma unroll
        for (int cc = ty; cc < 32; cc += 8)
            tile[cc][tx] = src[(size_t)cc * HW + tx];
        __syncthreads();
        size_t slab = (size_t)(b * 8 + h) * HWSUM + pos0;
#pragma unroll
        for (int ii = ty; ii < 32; ii += 8)
            ft[(slab + ii) * 32 + tx] = f2bf(tile[tx][ii]);
    }
}

// ---------------------------------------------------------------------------
// Sampler pipeline helpers (round-6 structure — fastest measured).
// ---------------------------------------------------------------------------
static __device__ __forceinline__ void issue4(
    const int4* sIp, const float4* sWp, const char* fb,
    int ebase, int J, int h, int cl2, bool hiLane,
    uint4 (&dst)[8], float2 (&wt)[4])
{
#pragma unroll
    for (int t = 0; t < 4; ++t) {
        int es = (ebase + J + t) ^ h;
        int4 I = sIp[es];
        float4 Wf = sWp[es];
        int xo = (hiLane ? I.z : 0) + cl2;
        wt[t] = hiLane ? make_float2(Wf.y, Wf.w) : make_float2(Wf.x, Wf.z);
        dst[2 * t]     = *(const uint4*)(fb + (size_t)(unsigned)(I.x + xo));
        dst[2 * t + 1] = *(const uint4*)(fb + (size_t)(unsigned)(I.y + xo));
    }
}

static __device__ __forceinline__ void consume4(
    const uint4 (&src)[8], const float2 (&wt)[4],
    f32x2& a01, f32x2& a23, f32x2& a45, f32x2& a67)
{
#pragma unroll
    for (int t = 0; t < 4; ++t) {
        float s0 = wt[t].x, s1 = wt[t].y;
        uint4 d0 = src[2 * t], d1 = src[2 * t + 1];
        a01 = fma2(s0, up2(d0.x), a01);
        a23 = fma2(s0, up2(d0.y), a23);
        a45 = fma2(s0, up2(d0.z), a45);
        a67 = fma2(s0, up2(d0.w), a67);
        a01 = fma2(s1, up2(d1.x), a01);
        a23 = fma2(s1, up2(d1.y), a23);
        a45 = fma2(s1, up2(d1.z), a45);
        a67 = fma2(s1, up2(d1.w), a67);
    }
}

// ---------------------------------------------------------------------------
// Deformable sampling. Block = 4 bucketed queries x 8 heads x 8 lanes.
// ~17.9 TB/s effective L2 on 64B gather segments — measured equilibrium.
// ---------------------------------------------------------------------------
__global__ __launch_bounds__(256, 4) void sample_kernel(
    const float* __restrict__ offs, const float* __restrict__ attnw,
    const float* __restrict__ refp, const unsigned short* __restrict__ ft,
    const int* __restrict__ order, unsigned short* __restrict__ aggb)
{
    __shared__ int4   sI[512];
    __shared__ float4 sW[512];
    int tid = threadIdx.x;
    int bid = blockIdx.x;
    int obid = (bid & 7) * 1360 + (bid >> 3);   // XCD-chunked swizzle

#pragma unroll
    for (int e = tid; e < 512; e += 256) {
        int qq = e >> 7, pc = e & 127;
        int bq = order[obid * 4 + qq];
        int h = pc >> 4, lvl = (pc >> 2) & 3;
        float2 off = *(const float2*)&offs[((size_t)bq * 128 + pc) * 2];
        float aw = attnw[(size_t)bq * 128 + pc];
        float2 rp = *(const float2*)&refp[(size_t)bq * 2];
        int b = (bq >= Qn) ? 1 : 0;
        int Wl = 128 >> lvl;
        int base = (lvl == 0) ? 0 : (lvl == 1) ? 16384 : (lvl == 2) ? 20480 : 21504;
        float x = (rp.x + 0.5f * off.x) * (float)(Wl - 1);
        float y = (rp.y + 0.5f * off.y) * (float)(Wl - 1);
        float xf = floorf(x), yf = floorf(y);
        int x0 = (int)xf, y0 = (int)yf;
        float wx1 = x - xf, wx0 = 1.0f - wx1;
        float wy1 = y - yf, wy0 = 1.0f - wy1;
        float vx0 = (x0 >= 0 && x0 < Wl) ? 1.0f : 0.0f;
        float vx1 = (x0 + 1 >= 0 && x0 + 1 < Wl) ? 1.0f : 0.0f;
        float vy0 = (y0 >= 0 && y0 < Wl) ? 1.0f : 0.0f;
        float vy1 = (y0 + 1 >= 0 && y0 + 1 < Wl) ? 1.0f : 0.0f;
        int xc0 = min(max(x0, 0), Wl - 1), xc1 = min(max(x0 + 1, 0), Wl - 1);
        int yc0 = min(max(y0, 0), Wl - 1), yc1 = min(max(y0 + 1, 0), Wl - 1);
        int slab = (b * 8 + h) * HWSUM + base;
        int es = e ^ h;                          // LDS bank swizzle
        sI[es] = make_int4((slab + yc0 * Wl + xc0) * 64,     // byte offsets
                           (slab + yc1 * Wl + xc0) * 64,
                           (xc1 - xc0) * 64, 0);
        sW[es] = make_float4(wx0 * wy0 * vx0 * vy0 * aw,
                             wx1 * wy0 * vx1 * vy0 * aw,
                             wx0 * wy1 * vx0 * vy1 * aw,
                             wx1 * wy1 * vx1 * vy1 * aw);
    }
    __syncthreads();

    int qq = tid >> 6;
    int h = (tid >> 3) & 7;
    int l = tid & 7;
    int cl2 = (l & 3) * 16;
    bool hiLane = (l & 4) != 0;
    const char* fb = (const char*)ft;
    f32x2 a01 = {0.f, 0.f}, a23 = {0.f, 0.f}, a45 = {0.f, 0.f}, a67 = {0.f, 0.f};
    int ebase = qq * 128 + h * 16;

    uint4 dA[8]; float2 wA[4];
    uint4 dB[8]; float2 wB[4];

    issue4(sI, sW, fb, ebase, 0, h, cl2, hiLane, dA, wA);
    issue4(sI, sW, fb, ebase, 4, h, cl2, hiLane, dB, wB);
    consume4(dA, wA, a01, a23, a45, a67);
    issue4(sI, sW, fb, ebase, 8, h, cl2, hiLane, dA, wA);
    consume4(dB, wB, a01, a23, a45, a67);
    issue4(sI, sW, fb, ebase, 12, h, cl2, hiLane, dB, wB);
    consume4(dA, wA, a01, a23, a45, a67);
    consume4(dB, wB, a01, a23, a45, a67);

    float av[8] = {a01.x, a01.y, a23.x, a23.y, a45.x, a45.y, a67.x, a67.y};
#pragma unroll
    for (int k = 0; k < 8; ++k) av[k] += __shfl_xor(av[k], 4);
    if (!hiLane) {
        int bq = order[obid * 4 + qq];
        uint4 o;
        o.x = (unsigned)f2bf(av[0]) | ((unsigned)f2bf(av[1]) << 16);
        o.y = (unsigned)f2bf(av[2]) | ((unsigned)f2bf(av[3]) << 16);
        o.z = (unsigned)f2bf(av[4]) | ((unsigned)f2bf(av[5]) << 16);
        o.w = (unsigned)f2bf(av[6]) | ((unsigned)f2bf(av[7]) << 16);
        *(uint4*)&aggb[(size_t)bq * 256 + h * 32 + (l & 3) * 8] = o;
    }
}

// ---------------------------------------------------------------------------
// bf16 MFMA GEMM for the output projection: C = A[M,256] @ Bt[N,256]^T + bias.
// ---------------------------------------------------------------------------
__global__ __launch_bounds__(256) void mfma_gemm(
    const unsigned short* __restrict__ Abf, const unsigned short* __restrict__ Bt,
    const float* __restrict__ bias, float* __restrict__ C, int N)
{
    __shared__ unsigned short As[128 * 32];
    __shared__ unsigned short Bs[128 * 32];
    int tid = threadIdx.x;
    int m0 = blockIdx.x * 128, n0 = blockIdx.y * 128;
    int wave = tid >> 6, lane = tid & 63;
    int wr = wave >> 1, wc = wave & 1;
    int lr = lane & 15, kb = (lane >> 4) * 8;
    int arow = tid >> 2, aseg = (tid & 3) * 8;
    const unsigned short* Ag = Abf + (size_t)(m0 + arow) * 256 + aseg;
    const unsigned short* Bg = Bt + (size_t)(n0 + arow) * 256 + aseg;
    f32x4 acc[4][4] = {};
    for (int kt = 0; kt < 256; kt += 32) {
        async16(Ag + kt,            &As[tid * 8]);
        async16(Ag + 64 * 256 + kt, &As[tid * 8 + 2048]);
        async16(Bg + kt,            &Bs[tid * 8]);
        async16(Bg + 64 * 256 + kt, &Bs[tid * 8 + 2048]);
        __syncthreads();
        bf16x8 af[4], bfr[4];
#pragma unroll
        for (int i = 0; i < 4; ++i) {
            af[i]  = *(const bf16x8*)&As[(wr * 64 + i * 16 + lr) * 32 + kb];
            bfr[i] = *(const bf16x8*)&Bs[(wc * 64 + i * 16 + lr) * 32 + kb];
        }
#pragma unroll
        for (int i = 0; i < 4; ++i)
#pragma unroll
            for (int j = 0; j < 4; ++j)
                acc[i][j] = __builtin_amdgcn_mfma_f32_16x16x32_bf16(
                    af[i], bfr[j], acc[i][j], 0, 0, 0);
        __syncthreads();
    }
    int crow = (lane >> 4) * 4;
#pragma unroll
    for (int j = 0; j < 4; ++j) {
        int gcol = n0 + wc * 64 + j * 16 + lr;
        float bv = bias[gcol];
#pragma unroll
        for (int i = 0; i < 4; ++i) {
            int grow = m0 + wr * 64 + i * 16 + crow;
#pragma unroll
            for (int r = 0; r < 4; ++r)
                C[(size_t)(grow + r) * N + gcol] = acc[i][j][r] + bv;
        }
    }
}

// ---------------------------------------------------------------------------
extern "C" void kernel_launch(void* const* d_in, const int* in_sizes, int n_in,
                              void* d_out, int out_size, void* d_ws, size_t ws_size,
                              hipStream_t stream)
{
    const float* query  = (const float*)d_in[0];
    const float* f0     = (const float*)d_in[1];
    const float* f1     = (const float*)d_in[2];
    const float* f2     = (const float*)d_in[3];
    const float* f3     = (const float*)d_in[4];
    const float* refp   = (const float*)d_in[5];
    const float* W_off  = (const float*)d_in[6];
    const float* b_off  = (const float*)d_in[7];
    const float* W_attn = (const float*)d_in[8];
    const float* b_attn = (const float*)d_in[9];
    const float* W_out  = (const float*)d_in[10];
    const float* b_out  = (const float*)d_in[11];

    float* out      = (float*)d_out;                       // (B,Q,256)
    float* attn_out = out + (size_t)BQ * 256;              // (B,Q,8,4,4)

    // Workspace layout (bytes):
    char* w = (char*)d_ws;
    float* offs          = (float*)(w + 0);                 // 44,564,480
    unsigned short* ft   = (unsigned short*)(w + 44564480); // 22,282,240
    unsigned short* aggb = (unsigned short*)(w + 66846720); // 22,282,240
    unsigned short* Wcat = (unsigned short*)(w + 89128960); // 196,608 [384][256] hi
    unsigned short* Wlo  = (unsigned short*)(w + 89325568); // 131,072 [256][256] lo
    unsigned short* wout = (unsigned short*)(w + 89456640); // 131,072
    int* hist            = (int*)(w + 89587712);            //   2,048
    int* cnt             = (int*)(w + 89589760);            //   2,048
    int* order           = (int*)(w + 89591808);            // 174,080

    // zero hist + cnt (contiguous 4KB), graph-capturable
    hipMemsetAsync(hist, 0, 4096, stream);

    // weight split + query histogram
    prep_kernel<<<dim3(330), 256, 0, stream>>>(
        W_off, W_attn, W_out, Wcat, Wlo, wout, refp, hist);

    // qproj + scatter(scan) + feat transpose, co-resident
    mega_kernel<<<dim3(11730), 256, 0, stream>>>(
        query, Wcat, Wlo, b_off, b_attn, offs, attn_out,
        f0, f1, f2, f3, ft, refp, hist, cnt, order);

    // sampling + aggregation -> agg bf16
    sample_kernel<<<dim3(10880), 256, 0, stream>>>(
        offs, attn_out, refp, ft, order, aggb);

    // out = agg @ W_out + b_out
    mfma_gemm<<<dim3(340, 2), 256, 0, stream>>>(aggb, wout, b_out, out, 256);
}

// Round 11
// 183.858 us; speedup vs baseline: 1.0194x; 1.0194x over previous
//
#include <hip/hip_runtime.h>
#include <hip/hip_bf16.h>

// Problem constants
#define Bn 2
#define Qn 21760
#define BQ 43520        // Bn*Qn
#define HWSUM 21760     // 128^2 + 64^2 + 32^2 + 16^2

typedef __attribute__((ext_vector_type(8))) short bf16x8;
typedef __attribute__((ext_vector_type(4))) float f32x4;
typedef __attribute__((ext_vector_type(2))) float f32x2;

static __device__ __forceinline__ unsigned short f2bf(float f) {
    __hip_bfloat16 h = __float2bfloat16(f);
    return __builtin_bit_cast(unsigned short, h);
}
static __device__ __forceinline__ float bf2f(unsigned short u) {
    return __uint_as_float(((unsigned)u) << 16);
}
static __device__ __forceinline__ void async16(const void* g, void* l) {
    __builtin_amdgcn_global_load_lds(
        (const __attribute__((address_space(1))) unsigned int*)g,
        (__attribute__((address_space(3))) unsigned int*)l, 16, 0, 0);
}
static __device__ __forceinline__ f32x2 up2(unsigned u) {
    uint2 t = make_uint2(u << 16, u & 0xffff0000u);
    return __builtin_bit_cast(f32x2, t);
}
static __device__ __forceinline__ f32x2 fma2(float s, f32x2 v, f32x2 a) {
    f32x2 sv = {s, s};
    return __builtin_elementwise_fma(sv, v, a);
}

#define PKPAIR(F0, F1, HP, LP) { \
        unsigned short h0_ = f2bf(F0), h1_ = f2bf(F1); \
        HP = (unsigned)h0_ | ((unsigned)h1_ << 16); \
        LP = (unsigned)f2bf((F0) - bf2f(h0_)) | ((unsigned)f2bf((F1) - bf2f(h1_)) << 16); }

static __device__ __forceinline__ int bin_of(const float* refp, int q) {
    float rx = refp[(size_t)q * 2], ry = refp[(size_t)q * 2 + 1];
    int cx = (int)(rx * 16.0f); cx = min(max(cx, 0), 15);
    int cy = (int)(ry * 16.0f); cy = min(max(cy, 0), 15);
    int m = 0;
#pragma unroll
    for (int i = 0; i < 4; ++i)
        m |= (((cx >> i) & 1) << (2 * i)) | (((cy >> i) & 1) << (2 * i + 1));
    return ((q >= Qn) ? 256 : 0) + m;
}

// ---------------------------------------------------------------------------
// Transpose feats (B, C=256, H, W) fp32 -> head-major (B, 8h, pos, 32ch) bf16.
// grid: (1360, 8 heads), block 256.  The y==0 slice ALSO builds the query
// histogram (hist zeroed by hipMemsetAsync earlier in the stream).
// ---------------------------------------------------------------------------
__global__ __launch_bounds__(256) void feat_transpose_kernel(
    const float* __restrict__ f0, const float* __restrict__ f1,
    const float* __restrict__ f2, const float* __restrict__ f3,
    const float* __restrict__ refp, int* hist,
    unsigned short* __restrict__ ft)
{
    __shared__ float tile[32][33];
    int bidx = blockIdx.x;
    if (blockIdx.y == 0) {                     // fused histogram
        int gid = bidx * 256 + threadIdx.x;
        if (gid < BQ) atomicAdd(&hist[bin_of(refp, gid)], 1);
    }
    int b = bidx / 680;
    int pos0 = (bidx - b * 680) * 32;
    int h = blockIdx.y;
    int c0 = h * 32;
    int lvl = (pos0 >= 21504) ? 3 : (pos0 >= 20480) ? 2 : (pos0 >= 16384) ? 1 : 0;
    int HW = 16384 >> (2 * lvl);
    int base = (lvl == 0) ? 0 : (lvl == 1) ? 16384 : (lvl == 2) ? 20480 : 21504;
    const float* f = (lvl == 0) ? f0 : (lvl == 1) ? f1 : (lvl == 2) ? f2 : f3;
    const float* src = f + (size_t)(b * 256 + c0) * HW + (pos0 - base);
    int tx = threadIdx.x & 31, ty = threadIdx.x >> 5;
#pragma unroll
    for (int cc = ty; cc < 32; cc += 8)
        tile[cc][tx] = src[(size_t)cc * HW + tx];
    __syncthreads();
    size_t slab = (size_t)(b * 8 + h) * HWSUM + pos0;
#pragma unroll
    for (int ii = ty; ii < 32; ii += 8)
        ft[(slab + ii) * 32 + tx] = f2bf(tile[tx][ii]);
}

// ---------------------------------------------------------------------------
// Scatter with redundant in-block 512-bin scan (r10-verified): kills the
// dedicated scan launch. grid 170 x 256 (170*256 == BQ exactly).
// ---------------------------------------------------------------------------
__global__ __launch_bounds__(256) void scatter_kernel(
    const float* __restrict__ refp, const int* __restrict__ hist,
    int* cnt, int* order)
{
    __shared__ int s[512];
    int t = threadIdx.x;
    int h0 = hist[t], h1 = hist[t + 256];
    s[t] = h0; s[t + 256] = h1;
    __syncthreads();
    for (int d = 1; d < 512; d <<= 1) {
        int v0 = (t >= d) ? s[t - d] : 0;
        int v1 = (t + 256 >= d) ? s[t + 256 - d] : 0;
        __syncthreads();
        s[t] += v0; s[t + 256] += v1;
        __syncthreads();
    }
    int e0 = s[t] - h0, e1 = s[t + 256] - h1;   // exclusive prefix
    __syncthreads();
    s[t] = e0; s[t + 256] = e1;
    __syncthreads();
    int q = blockIdx.x * 256 + t;
    int b = bin_of(refp, q);
    int idx = s[b] + atomicAdd(&cnt[b], 1);
    order[idx] = q;
}

// ---------------------------------------------------------------------------
// Merged weight split+transpose for all three weight matrices.
// grid (20, 8): bx<8 -> W_off (with lo), bx<12 -> W_attn, else -> W_out.
// ---------------------------------------------------------------------------
__global__ __launch_bounds__(256) void wsplit_all_kernel(
    const float* __restrict__ Woff, const float* __restrict__ Wattn,
    const float* __restrict__ Wout,
    unsigned short* __restrict__ Wcat, unsigned short* __restrict__ Wlo,
    unsigned short* __restrict__ woutT)
{
    __shared__ float tile[32][33];
    int bx = blockIdx.x;
    const float* W;
    unsigned short* bthi;
    unsigned short* btlo = nullptr;
    int N, dolo, nb;
    if (bx < 8)       { W = Woff;  bthi = Wcat;             btlo = Wlo; N = 256; dolo = 1; nb = bx; }
    else if (bx < 12) { W = Wattn; bthi = Wcat + 256 * 256; N = 128; dolo = 0; nb = bx - 8; }
    else              { W = Wout;  bthi = woutT;            N = 256; dolo = 0; nb = bx - 12; }
    int n0 = nb * 32, k0 = blockIdx.y * 32;
    int tx = threadIdx.x & 31, ty = threadIdx.x >> 5;
#pragma unroll
    for (int r = ty; r < 32; r += 8)
        tile[r][tx] = W[(size_t)(k0 + r) * N + n0 + tx];
    __syncthreads();
#pragma unroll
    for (int r = ty; r < 32; r += 8) {
        float v = tile[tx][r];
        unsigned short h = f2bf(v);
        bthi[(size_t)(n0 + r) * 256 + k0 + tx] = h;
        if (dolo) btlo[(size_t)(n0 + r) * 256 + k0 + tx] = f2bf(v - bf2f(h));
    }
}

// ---------------------------------------------------------------------------
// Fused query projection, single pass over A. Block = 64 rows x 384 cols.
// Cols 0..255: offsets (split-precision 3-term MFMA + tanh).
// Cols 256..383: attn scores (1-term) + in-register softmax over 16-groups.
// ---------------------------------------------------------------------------
__global__ __launch_bounds__(256, 3) void qproj_kernel(
    const float* __restrict__ A,
    const unsigned short* __restrict__ Wcat,   // [384][256] bf16 hi
    const unsigned short* __restrict__ Wlo,    // [256][256] bf16 lo (offset cols)
    const float* __restrict__ b_off, const float* __restrict__ b_attn,
    float* __restrict__ offs, float* __restrict__ attn_out)
{
    __shared__ unsigned short Ah[64 * 32], Al[64 * 32];
    __shared__ unsigned short Bh[384 * 32];
    __shared__ unsigned short Bl[256 * 32];
    int tid = threadIdx.x;
    int m0 = blockIdx.x * 64;
    int wave = tid >> 6, lane = tid & 63;
    int wr = wave >> 1, wc = wave & 1;
    int lr = lane & 15, kb = (lane >> 4) * 8;
    int srow = tid >> 2, sseg = (tid & 3) * 8;
    const float* Ag = A + (size_t)(m0 + srow) * 256 + sseg;

    f32x4 acc[2][12] = {};

    for (int kt = 0; kt < 256; kt += 32) {
#pragma unroll
        for (int p = 0; p < 6; ++p) {
            int tile = tid + p * 256;
            int row = tile >> 2, seg = tile & 3;
            async16(Wcat + (size_t)row * 256 + kt + seg * 8, &Bh[tile * 8]);
        }
#pragma unroll
        for (int p = 0; p < 4; ++p) {
            int tile = tid + p * 256;
            int row = tile >> 2, seg = tile & 3;
            async16(Wlo + (size_t)row * 256 + kt + seg * 8, &Bl[tile * 8]);
        }
        float4 q0 = *(const float4*)(Ag + kt);
        float4 q1 = *(const float4*)(Ag + kt + 4);
        uint4 HP, LP;
        PKPAIR(q0.x, q0.y, HP.x, LP.x); PKPAIR(q0.z, q0.w, HP.y, LP.y);
        PKPAIR(q1.x, q1.y, HP.z, LP.z); PKPAIR(q1.z, q1.w, HP.w, LP.w);
        *(uint4*)&Ah[srow * 32 + sseg] = HP;
        *(uint4*)&Al[srow * 32 + sseg] = LP;
        __syncthreads();

        bf16x8 ah[2], al[2];
#pragma unroll
        for (int i = 0; i < 2; ++i) {
            ah[i] = *(const bf16x8*)&Ah[(wr * 32 + i * 16 + lr) * 32 + kb];
            al[i] = *(const bf16x8*)&Al[(wr * 32 + i * 16 + lr) * 32 + kb];
        }
#pragma unroll
        for (int j = 0; j < 12; ++j) {
            int c16 = j * 2 + wc;
            bf16x8 bh = *(const bf16x8*)&Bh[(c16 * 16 + lr) * 32 + kb];
            if (j < 8) {
                bf16x8 bl = *(const bf16x8*)&Bl[(c16 * 16 + lr) * 32 + kb];
#pragma unroll
                for (int i = 0; i < 2; ++i) {
                    acc[i][j] = __builtin_amdgcn_mfma_f32_16x16x32_bf16(ah[i], bh, acc[i][j], 0, 0, 0);
                    acc[i][j] = __builtin_amdgcn_mfma_f32_16x16x32_bf16(al[i], bh, acc[i][j], 0, 0, 0);
                    acc[i][j] = __builtin_amdgcn_mfma_f32_16x16x32_bf16(ah[i], bl, acc[i][j], 0, 0, 0);
                }
            } else {
#pragma unroll
                for (int i = 0; i < 2; ++i)
                    acc[i][j] = __builtin_amdgcn_mfma_f32_16x16x32_bf16(ah[i], bh, acc[i][j], 0, 0, 0);
            }
        }
        __syncthreads();
    }

    int crow = (lane >> 4) * 4;
#pragma unroll
    for (int j = 0; j < 12; ++j) {
        int c16 = j * 2 + wc;
        if (j < 8) {
            int col = c16 * 16 + lr;
            float bv = b_off[col];
#pragma unroll
            for (int i = 0; i < 2; ++i) {
                int grow = m0 + wr * 32 + i * 16 + crow;
#pragma unroll
                for (int r = 0; r < 4; ++r)
                    offs[(size_t)(grow + r) * 256 + col] = tanhf(acc[i][j][r] + bv);
            }
        } else {
            int col = (c16 - 16) * 16 + lr;
            float bv = b_attn[col];
#pragma unroll
            for (int i = 0; i < 2; ++i) {
                int grow = m0 + wr * 32 + i * 16 + crow;
#pragma unroll
                for (int r = 0; r < 4; ++r) {
                    float v = acc[i][j][r] + bv;
                    float mx = v;
                    mx = fmaxf(mx, __shfl_xor(mx, 1));
                    mx = fmaxf(mx, __shfl_xor(mx, 2));
                    mx = fmaxf(mx, __shfl_xor(mx, 4));
                    mx = fmaxf(mx, __shfl_xor(mx, 8));
                    float e = expf(v - mx);
                    float s = e;
                    s += __shfl_xor(s, 1);
                    s += __shfl_xor(s, 2);
                    s += __shfl_xor(s, 4);
                    s += __shfl_xor(s, 8);
                    attn_out[(size_t)(grow + r) * 128 + col] = e / s;
                }
            }
        }
    }
}

// ---------------------------------------------------------------------------
// Sampler pipeline helpers (round-6 structure — fastest measured).
// ---------------------------------------------------------------------------
static __device__ __forceinline__ void issue4(
    const int4* sIp, const float4* sWp, const char* fb,
    int ebase, int J, int h, int cl2, bool hiLane,
    uint4 (&dst)[8], float2 (&wt)[4])
{
#pragma unroll
    for (int t = 0; t < 4; ++t) {
        int es = (ebase + J + t) ^ h;
        int4 I = sIp[es];
        float4 Wf = sWp[es];
        int xo = (hiLane ? I.z : 0) + cl2;
        wt[t] = hiLane ? make_float2(Wf.y, Wf.w) : make_float2(Wf.x, Wf.z);
        dst[2 * t]     = *(const uint4*)(fb + (size_t)(unsigned)(I.x + xo));
        dst[2 * t + 1] = *(const uint4*)(fb + (size_t)(unsigned)(I.y + xo));
    }
}

static __device__ __forceinline__ void consume4(
    const uint4 (&src)[8], const float2 (&wt)[4],
    f32x2& a01, f32x2& a23, f32x2& a45, f32x2& a67)
{
#pragma unroll
    for (int t = 0; t < 4; ++t) {
        float s0 = wt[t].x, s1 = wt[t].y;
        uint4 d0 = src[2 * t], d1 = src[2 * t + 1];
        a01 = fma2(s0, up2(d0.x), a01);
        a23 = fma2(s0, up2(d0.y), a23);
        a45 = fma2(s0, up2(d0.z), a45);
        a67 = fma2(s0, up2(d0.w), a67);
        a01 = fma2(s1, up2(d1.x), a01);
        a23 = fma2(s1, up2(d1.y), a23);
        a45 = fma2(s1, up2(d1.z), a45);
        a67 = fma2(s1, up2(d1.w), a67);
    }
}

// ---------------------------------------------------------------------------
// Deformable sampling. Block = 4 bucketed queries x 8 heads x 8 lanes.
// ~17.9 TB/s effective L2 on 64B gather segments — measured equilibrium
// (r7 sched_barrier and r8 asm-vmcnt pipelines did not beat it).
// ---------------------------------------------------------------------------
__global__ __launch_bounds__(256, 4) void sample_kernel(
    const float* __restrict__ offs, const float* __restrict__ attnw,
    const float* __restrict__ refp, const unsigned short* __restrict__ ft,
    const int* __restrict__ order, unsigned short* __restrict__ aggb)
{
    __shared__ int4   sI[512];
    __shared__ float4 sW[512];
    int tid = threadIdx.x;
    int bid = blockIdx.x;
    int obid = (bid & 7) * 1360 + (bid >> 3);   // XCD-chunked swizzle

#pragma unroll
    for (int e = tid; e < 512; e += 256) {
        int qq = e >> 7, pc = e & 127;
        int bq = order[obid * 4 + qq];
        int h = pc >> 4, lvl = (pc >> 2) & 3;
        float2 off = *(const float2*)&offs[((size_t)bq * 128 + pc) * 2];
        float aw = attnw[(size_t)bq * 128 + pc];
        float2 rp = *(const float2*)&refp[(size_t)bq * 2];
        int b = (bq >= Qn) ? 1 : 0;
        int Wl = 128 >> lvl;
        int base = (lvl == 0) ? 0 : (lvl == 1) ? 16384 : (lvl == 2) ? 20480 : 21504;
        float x = (rp.x + 0.5f * off.x) * (float)(Wl - 1);
        float y = (rp.y + 0.5f * off.y) * (float)(Wl - 1);
        float xf = floorf(x), yf = floorf(y);
        int x0 = (int)xf, y0 = (int)yf;
        float wx1 = x - xf, wx0 = 1.0f - wx1;
        float wy1 = y - yf, wy0 = 1.0f - wy1;
        float vx0 = (x0 >= 0 && x0 < Wl) ? 1.0f : 0.0f;
        float vx1 = (x0 + 1 >= 0 && x0 + 1 < Wl) ? 1.0f : 0.0f;
        float vy0 = (y0 >= 0 && y0 < Wl) ? 1.0f : 0.0f;
        float vy1 = (y0 + 1 >= 0 && y0 + 1 < Wl) ? 1.0f : 0.0f;
        int xc0 = min(max(x0, 0), Wl - 1), xc1 = min(max(x0 + 1, 0), Wl - 1);
        int yc0 = min(max(y0, 0), Wl - 1), yc1 = min(max(y0 + 1, 0), Wl - 1);
        int slab = (b * 8 + h) * HWSUM + base;
        int es = e ^ h;                          // LDS bank swizzle
        sI[es] = make_int4((slab + yc0 * Wl + xc0) * 64,     // byte offsets
                           (slab + yc1 * Wl + xc0) * 64,
                           (xc1 - xc0) * 64, 0);
        sW[es] = make_float4(wx0 * wy0 * vx0 * vy0 * aw,
                             wx1 * wy0 * vx1 * vy0 * aw,
                             wx0 * wy1 * vx0 * vy1 * aw,
                             wx1 * wy1 * vx1 * vy1 * aw);
    }
    __syncthreads();

    int qq = tid >> 6;
    int h = (tid >> 3) & 7;
    int l = tid & 7;
    int cl2 = (l & 3) * 16;
    bool hiLane = (l & 4) != 0;
    const char* fb = (const char*)ft;
    f32x2 a01 = {0.f, 0.f}, a23 = {0.f, 0.f}, a45 = {0.f, 0.f}, a67 = {0.f, 0.f};
    int ebase = qq * 128 + h * 16;

    uint4 dA[8]; float2 wA[4];
    uint4 dB[8]; float2 wB[4];

    issue4(sI, sW, fb, ebase, 0, h, cl2, hiLane, dA, wA);
    issue4(sI, sW, fb, ebase, 4, h, cl2, hiLane, dB, wB);
    consume4(dA, wA, a01, a23, a45, a67);
    issue4(sI, sW, fb, ebase, 8, h, cl2, hiLane, dA, wA);
    consume4(dB, wB, a01, a23, a45, a67);
    issue4(sI, sW, fb, ebase, 12, h, cl2, hiLane, dB, wB);
    consume4(dA, wA, a01, a23, a45, a67);
    consume4(dB, wB, a01, a23, a45, a67);

    float av[8] = {a01.x, a01.y, a23.x, a23.y, a45.x, a45.y, a67.x, a67.y};
#pragma unroll
    for (int k = 0; k < 8; ++k) av[k] += __shfl_xor(av[k], 4);
    if (!hiLane) {
        int bq = order[obid * 4 + qq];
        uint4 o;
        o.x = (unsigned)f2bf(av[0]) | ((unsigned)f2bf(av[1]) << 16);
        o.y = (unsigned)f2bf(av[2]) | ((unsigned)f2bf(av[3]) << 16);
        o.z = (unsigned)f2bf(av[4]) | ((unsigned)f2bf(av[5]) << 16);
        o.w = (unsigned)f2bf(av[6]) | ((unsigned)f2bf(av[7]) << 16);
        *(uint4*)&aggb[(size_t)bq * 256 + h * 32 + (l & 3) * 8] = o;
    }
}

// ---------------------------------------------------------------------------
// bf16 MFMA GEMM for the output projection: C = A[M,256] @ Bt[N,256]^T + bias.
// ---------------------------------------------------------------------------
__global__ __launch_bounds__(256) void mfma_gemm(
    const unsigned short* __restrict__ Abf, const unsigned short* __restrict__ Bt,
    const float* __restrict__ bias, float* __restrict__ C, int N)
{
    __shared__ unsigned short As[128 * 32];
    __shared__ unsigned short Bs[128 * 32];
    int tid = threadIdx.x;
    int m0 = blockIdx.x * 128, n0 = blockIdx.y * 128;
    int wave = tid >> 6, lane = tid & 63;
    int wr = wave >> 1, wc = wave & 1;
    int lr = lane & 15, kb = (lane >> 4) * 8;
    int arow = tid >> 2, aseg = (tid & 3) * 8;
    const unsigned short* Ag = Abf + (size_t)(m0 + arow) * 256 + aseg;
    const unsigned short* Bg = Bt + (size_t)(n0 + arow) * 256 + aseg;
    f32x4 acc[4][4] = {};
    for (int kt = 0; kt < 256; kt += 32) {
        async16(Ag + kt,            &As[tid * 8]);
        async16(Ag + 64 * 256 + kt, &As[tid * 8 + 2048]);
        async16(Bg + kt,            &Bs[tid * 8]);
        async16(Bg + 64 * 256 + kt, &Bs[tid * 8 + 2048]);
        __syncthreads();
        bf16x8 af[4], bfr[4];
#pragma unroll
        for (int i = 0; i < 4; ++i) {
            af[i]  = *(const bf16x8*)&As[(wr * 64 + i * 16 + lr) * 32 + kb];
            bfr[i] = *(const bf16x8*)&Bs[(wc * 64 + i * 16 + lr) * 32 + kb];
        }
#pragma unroll
        for (int i = 0; i < 4; ++i)
#pragma unroll
            for (int j = 0; j < 4; ++j)
                acc[i][j] = __builtin_amdgcn_mfma_f32_16x16x32_bf16(
                    af[i], bfr[j], acc[i][j], 0, 0, 0);
        __syncthreads();
    }
    int crow = (lane >> 4) * 4;
#pragma unroll
    for (int j = 0; j < 4; ++j) {
        int gcol = n0 + wc * 64 + j * 16 + lr;
        float bv = bias[gcol];
#pragma unroll
        for (int i = 0; i < 4; ++i) {
            int grow = m0 + wr * 64 + i * 16 + crow;
#pragma unroll
            for (int r = 0; r < 4; ++r)
                C[(size_t)(grow + r) * N + gcol] = acc[i][j][r] + bv;
        }
    }
}

// ---------------------------------------------------------------------------
extern "C" void kernel_launch(void* const* d_in, const int* in_sizes, int n_in,
                              void* d_out, int out_size, void* d_ws, size_t ws_size,
                              hipStream_t stream)
{
    const float* query  = (const float*)d_in[0];
    const float* f0     = (const float*)d_in[1];
    const float* f1     = (const float*)d_in[2];
    const float* f2     = (const float*)d_in[3];
    const float* f3     = (const float*)d_in[4];
    const float* refp   = (const float*)d_in[5];
    const float* W_off  = (const float*)d_in[6];
    const float* b_off  = (const float*)d_in[7];
    const float* W_attn = (const float*)d_in[8];
    const float* b_attn = (const float*)d_in[9];
    const float* W_out  = (const float*)d_in[10];
    const float* b_out  = (const float*)d_in[11];

    float* out      = (float*)d_out;                       // (B,Q,256)
    float* attn_out = out + (size_t)BQ * 256;              // (B,Q,8,4,4)

    // Workspace layout (bytes):
    char* w = (char*)d_ws;
    float* offs          = (float*)(w + 0);                 // 44,564,480
    unsigned short* ft   = (unsigned short*)(w + 44564480); // 22,282,240
    unsigned short* aggb = (unsigned short*)(w + 66846720); // 22,282,240
    unsigned short* Wcat = (unsigned short*)(w + 89128960); // 196,608 [384][256] hi
    unsigned short* Wlo  = (unsigned short*)(w + 89325568); // 131,072 [256][256] lo
    unsigned short* wout = (unsigned short*)(w + 89456640); // 131,072
    int* hist            = (int*)(w + 89587712);            //   2,048
    int* cnt             = (int*)(w + 89589760);            //   2,048
    int* order           = (int*)(w + 89591808);            // 174,080

    // zero hist + cnt (contiguous 4KB), graph-capturable
    hipMemsetAsync(hist, 0, 4096, stream);

    // transpose + fused histogram
    feat_transpose_kernel<<<dim3(1360, 8), 256, 0, stream>>>(
        f0, f1, f2, f3, refp, hist, ft);
    // weight split
    wsplit_all_kernel<<<dim3(20, 8), 256, 0, stream>>>(
        W_off, W_attn, W_out, Wcat, Wlo, wout);
    // offsets + attn + softmax
    qproj_kernel<<<dim3(680), 256, 0, stream>>>(
        query, Wcat, Wlo, b_off, b_attn, offs, attn_out);
    // bucketed order (scan folded into scatter)
    scatter_kernel<<<dim3(170), 256, 0, stream>>>(refp, hist, cnt, order);
    // sampling + aggregation -> agg bf16
    sample_kernel<<<dim3(10880), 256, 0, stream>>>(
        offs, attn_out, refp, ft, order, aggb);
    // out = agg @ W_out + b_out
    mfma_gemm<<<dim3(340, 2), 256, 0, stream>>>(aggb, wout, b_out, out, 256);
}

// Round 12
// 182.642 us; speedup vs baseline: 1.0262x; 1.0067x over previous
//
#include <hip/hip_runtime.h>
#include <hip/hip_bf16.h>

// Problem constants
#define Bn 2
#define Qn 21760
#define BQ 43520        // Bn*Qn
#define HWSUM 21760     // 128^2 + 64^2 + 32^2 + 16^2

typedef __attribute__((ext_vector_type(8))) short bf16x8;
typedef __attribute__((ext_vector_type(4))) float f32x4;
typedef __attribute__((ext_vector_type(2))) float f32x2;

static __device__ __forceinline__ unsigned short f2bf(float f) {
    __hip_bfloat16 h = __float2bfloat16(f);
    return __builtin_bit_cast(unsigned short, h);
}
static __device__ __forceinline__ float bf2f(unsigned short u) {
    return __uint_as_float(((unsigned)u) << 16);
}
static __device__ __forceinline__ void async16(const void* g, void* l) {
    __builtin_amdgcn_global_load_lds(
        (const __attribute__((address_space(1))) unsigned int*)g,
        (__attribute__((address_space(3))) unsigned int*)l, 16, 0, 0);
}
static __device__ __forceinline__ f32x2 up2(unsigned u) {
    uint2 t = make_uint2(u << 16, u & 0xffff0000u);
    return __builtin_bit_cast(f32x2, t);
}
static __device__ __forceinline__ f32x2 fma2(float s, f32x2 v, f32x2 a) {
    f32x2 sv = {s, s};
    return __builtin_elementwise_fma(sv, v, a);
}

#define PKPAIR(F0, F1, HP, LP) { \
        unsigned short h0_ = f2bf(F0), h1_ = f2bf(F1); \
        HP = (unsigned)h0_ | ((unsigned)h1_ << 16); \
        LP = (unsigned)f2bf((F0) - bf2f(h0_)) | ((unsigned)f2bf((F1) - bf2f(h1_)) << 16); }

static __device__ __forceinline__ int bin_of(const float* refp, int q) {
    float rx = refp[(size_t)q * 2], ry = refp[(size_t)q * 2 + 1];
    int cx = (int)(rx * 16.0f); cx = min(max(cx, 0), 15);
    int cy = (int)(ry * 16.0f); cy = min(max(cy, 0), 15);
    int m = 0;
#pragma unroll
    for (int i = 0; i < 4; ++i)
        m |= (((cx >> i) & 1) << (2 * i)) | (((cy >> i) & 1) << (2 * i + 1));
    return ((q >= Qn) ? 256 : 0) + m;
}

// ---------------------------------------------------------------------------
// Transpose + wsplit + histogram, one launch (homogeneous footprint: 4KB LDS,
// 256 threads, low VGPR — unlike r10's mega fusion, nothing is over-allocated).
//   blocks [0,160)       : weight split+transpose (needed first by qproj)
//   blocks [160,11040)   : feat transpose; the h==0 slice also builds hist
// ---------------------------------------------------------------------------
__global__ __launch_bounds__(256) void transpose_prep_kernel(
    const float* __restrict__ f0, const float* __restrict__ f1,
    const float* __restrict__ f2, const float* __restrict__ f3,
    const float* __restrict__ refp, int* hist,
    unsigned short* __restrict__ ft,
    const float* __restrict__ Woff, const float* __restrict__ Wattn,
    const float* __restrict__ Wout,
    unsigned short* __restrict__ Wcat, unsigned short* __restrict__ Wlo,
    unsigned short* __restrict__ woutT)
{
    __shared__ float tile[32][33];
    int bid = blockIdx.x;
    int tx = threadIdx.x & 31, ty = threadIdx.x >> 5;

    if (bid < 160) {
        // ---- weight split+transpose ----
        int bx = bid % 20, k8 = bid / 20;
        const float* W;
        unsigned short* bthi;
        unsigned short* btlo = nullptr;
        int N, dolo, nb;
        if (bx < 8)       { W = Woff;  bthi = Wcat;             btlo = Wlo; N = 256; dolo = 1; nb = bx; }
        else if (bx < 12) { W = Wattn; bthi = Wcat + 256 * 256; N = 128; dolo = 0; nb = bx - 8; }
        else              { W = Wout;  bthi = woutT;            N = 256; dolo = 0; nb = bx - 12; }
        int n0 = nb * 32, k0 = k8 * 32;
#pragma unroll
        for (int r = ty; r < 32; r += 8)
            tile[r][tx] = W[(size_t)(k0 + r) * N + n0 + tx];
        __syncthreads();
#pragma unroll
        for (int r = ty; r < 32; r += 8) {
            float v = tile[tx][r];
            unsigned short h = f2bf(v);
            bthi[(size_t)(n0 + r) * 256 + k0 + tx] = h;
            if (dolo) btlo[(size_t)(n0 + r) * 256 + k0 + tx] = f2bf(v - bf2f(h));
        }
        return;
    }

    // ---- feat transpose (+ histogram on the h==0 slice) ----
    int idx = bid - 160;
    int bidx = idx % 1360;
    int h = idx / 1360;
    if (h == 0) {
        int gid = bidx * 256 + threadIdx.x;
        if (gid < BQ) atomicAdd(&hist[bin_of(refp, gid)], 1);
    }
    int b = bidx / 680;
    int pos0 = (bidx - b * 680) * 32;
    int c0 = h * 32;
    int lvl = (pos0 >= 21504) ? 3 : (pos0 >= 20480) ? 2 : (pos0 >= 16384) ? 1 : 0;
    int HW = 16384 >> (2 * lvl);
    int base = (lvl == 0) ? 0 : (lvl == 1) ? 16384 : (lvl == 2) ? 20480 : 21504;
    const float* f = (lvl == 0) ? f0 : (lvl == 1) ? f1 : (lvl == 2) ? f2 : f3;
    const float* src = f + (size_t)(b * 256 + c0) * HW + (pos0 - base);
#pragma unroll
    for (int cc = ty; cc < 32; cc += 8)
        tile[cc][tx] = src[(size_t)cc * HW + tx];
    __syncthreads();
    size_t slab = (size_t)(b * 8 + h) * HWSUM + pos0;
#pragma unroll
    for (int ii = ty; ii < 32; ii += 8)
        ft[(slab + ii) * 32 + tx] = f2bf(tile[tx][ii]);
}

// ---------------------------------------------------------------------------
// Fused query projection + scatter. grid 850:
//   blocks [0,680)   : qproj — 64 rows x 384 cols; offset cols (0..255)
//                      split-precision 3-term + tanh; attn cols + softmax.
//   blocks [680,850) : scatter with redundant in-block 512-bin scan
//                      (aliases 2KB of the qproj LDS; hist complete from
//                      the previous dispatch).
// ---------------------------------------------------------------------------
__global__ __launch_bounds__(256, 3) void qproj_kernel(
    const float* __restrict__ A,
    const unsigned short* __restrict__ Wcat,   // [384][256] bf16 hi
    const unsigned short* __restrict__ Wlo,    // [256][256] bf16 lo (offset cols)
    const float* __restrict__ b_off, const float* __restrict__ b_attn,
    float* __restrict__ offs, float* __restrict__ attn_out,
    const float* __restrict__ refp, const int* __restrict__ hist,
    int* cnt, int* order)
{
    __shared__ unsigned short Ah[64 * 32], Al[64 * 32];
    __shared__ unsigned short Bh[384 * 32];
    __shared__ unsigned short Bl[256 * 32];
    int tid = threadIdx.x;
    int bid = blockIdx.x;

    if (bid >= 680) {
        // ---- scatter with in-block scan ----
        int* s = (int*)Ah;
        int t = tid;
        int h0 = hist[t], h1 = hist[t + 256];
        s[t] = h0; s[t + 256] = h1;
        __syncthreads();
        for (int d = 1; d < 512; d <<= 1) {
            int v0 = (t >= d) ? s[t - d] : 0;
            int v1 = (t + 256 >= d) ? s[t + 256 - d] : 0;
            __syncthreads();
            s[t] += v0; s[t + 256] += v1;
            __syncthreads();
        }
        int e0 = s[t] - h0, e1 = s[t + 256] - h1;   // exclusive prefix
        __syncthreads();
        s[t] = e0; s[t + 256] = e1;
        __syncthreads();
        int q = (bid - 680) * 256 + t;              // 170*256 == BQ exactly
        int b = bin_of(refp, q);
        int idx = s[b] + atomicAdd(&cnt[b], 1);
        order[idx] = q;
        return;
    }

    int m0 = bid * 64;
    int wave = tid >> 6, lane = tid & 63;
    int wr = wave >> 1, wc = wave & 1;
    int lr = lane & 15, kb = (lane >> 4) * 8;
    int srow = tid >> 2, sseg = (tid & 3) * 8;
    const float* Ag = A + (size_t)(m0 + srow) * 256 + sseg;

    f32x4 acc[2][12] = {};

    for (int kt = 0; kt < 256; kt += 32) {
#pragma unroll
        for (int p = 0; p < 6; ++p) {
            int tile = tid + p * 256;
            int row = tile >> 2, seg = tile & 3;
            async16(Wcat + (size_t)row * 256 + kt + seg * 8, &Bh[tile * 8]);
        }
#pragma unroll
        for (int p = 0; p < 4; ++p) {
            int tile = tid + p * 256;
            int row = tile >> 2, seg = tile & 3;
            async16(Wlo + (size_t)row * 256 + kt + seg * 8, &Bl[tile * 8]);
        }
        float4 q0 = *(const float4*)(Ag + kt);
        float4 q1 = *(const float4*)(Ag + kt + 4);
        uint4 HP, LP;
        PKPAIR(q0.x, q0.y, HP.x, LP.x); PKPAIR(q0.z, q0.w, HP.y, LP.y);
        PKPAIR(q1.x, q1.y, HP.z, LP.z); PKPAIR(q1.z, q1.w, HP.w, LP.w);
        *(uint4*)&Ah[srow * 32 + sseg] = HP;
        *(uint4*)&Al[srow * 32 + sseg] = LP;
        __syncthreads();

        bf16x8 ah[2], al[2];
#pragma unroll
        for (int i = 0; i < 2; ++i) {
            ah[i] = *(const bf16x8*)&Ah[(wr * 32 + i * 16 + lr) * 32 + kb];
            al[i] = *(const bf16x8*)&Al[(wr * 32 + i * 16 + lr) * 32 + kb];
        }
#pragma unroll
        for (int j = 0; j < 12; ++j) {
            int c16 = j * 2 + wc;
            bf16x8 bh = *(const bf16x8*)&Bh[(c16 * 16 + lr) * 32 + kb];
            if (j < 8) {
                bf16x8 bl = *(const bf16x8*)&Bl[(c16 * 16 + lr) * 32 + kb];
#pragma unroll
                for (int i = 0; i < 2; ++i) {
                    acc[i][j] = __builtin_amdgcn_mfma_f32_16x16x32_bf16(ah[i], bh, acc[i][j], 0, 0, 0);
                    acc[i][j] = __builtin_amdgcn_mfma_f32_16x16x32_bf16(al[i], bh, acc[i][j], 0, 0, 0);
                    acc[i][j] = __builtin_amdgcn_mfma_f32_16x16x32_bf16(ah[i], bl, acc[i][j], 0, 0, 0);
                }
            } else {
#pragma unroll
                for (int i = 0; i < 2; ++i)
                    acc[i][j] = __builtin_amdgcn_mfma_f32_16x16x32_bf16(ah[i], bh, acc[i][j], 0, 0, 0);
            }
        }
        __syncthreads();
    }

    int crow = (lane >> 4) * 4;
#pragma unroll
    for (int j = 0; j < 12; ++j) {
        int c16 = j * 2 + wc;
        if (j < 8) {
            int col = c16 * 16 + lr;
            float bv = b_off[col];
#pragma unroll
            for (int i = 0; i < 2; ++i) {
                int grow = m0 + wr * 32 + i * 16 + crow;
#pragma unroll
                for (int r = 0; r < 4; ++r)
                    offs[(size_t)(grow + r) * 256 + col] = tanhf(acc[i][j][r] + bv);
            }
        } else {
            int col = (c16 - 16) * 16 + lr;
            float bv = b_attn[col];
#pragma unroll
            for (int i = 0; i < 2; ++i) {
                int grow = m0 + wr * 32 + i * 16 + crow;
#pragma unroll
                for (int r = 0; r < 4; ++r) {
                    float v = acc[i][j][r] + bv;
                    float mx = v;
                    mx = fmaxf(mx, __shfl_xor(mx, 1));
                    mx = fmaxf(mx, __shfl_xor(mx, 2));
                    mx = fmaxf(mx, __shfl_xor(mx, 4));
                    mx = fmaxf(mx, __shfl_xor(mx, 8));
                    float e = expf(v - mx);
                    float s = e;
                    s += __shfl_xor(s, 1);
                    s += __shfl_xor(s, 2);
                    s += __shfl_xor(s, 4);
                    s += __shfl_xor(s, 8);
                    attn_out[(size_t)(grow + r) * 128 + col] = e / s;
                }
            }
        }
    }
}

// ---------------------------------------------------------------------------
// Sampler pipeline helpers (round-6 structure — fastest measured).
// ---------------------------------------------------------------------------
static __device__ __forceinline__ void issue4(
    const int4* sIp, const float4* sWp, const char* fb,
    int ebase, int J, int h, int cl2, bool hiLane,
    uint4 (&dst)[8], float2 (&wt)[4])
{
#pragma unroll
    for (int t = 0; t < 4; ++t) {
        int es = (ebase + J + t) ^ h;
        int4 I = sIp[es];
        float4 Wf = sWp[es];
        int xo = (hiLane ? I.z : 0) + cl2;
        wt[t] = hiLane ? make_float2(Wf.y, Wf.w) : make_float2(Wf.x, Wf.z);
        dst[2 * t]     = *(const uint4*)(fb + (size_t)(unsigned)(I.x + xo));
        dst[2 * t + 1] = *(const uint4*)(fb + (size_t)(unsigned)(I.y + xo));
    }
}

static __device__ __forceinline__ void consume4(
    const uint4 (&src)[8], const float2 (&wt)[4],
    f32x2& a01, f32x2& a23, f32x2& a45, f32x2& a67)
{
#pragma unroll
    for (int t = 0; t < 4; ++t) {
        float s0 = wt[t].x, s1 = wt[t].y;
        uint4 d0 = src[2 * t], d1 = src[2 * t + 1];
        a01 = fma2(s0, up2(d0.x), a01);
        a23 = fma2(s0, up2(d0.y), a23);
        a45 = fma2(s0, up2(d0.z), a45);
        a67 = fma2(s0, up2(d0.w), a67);
        a01 = fma2(s1, up2(d1.x), a01);
        a23 = fma2(s1, up2(d1.y), a23);
        a45 = fma2(s1, up2(d1.z), a45);
        a67 = fma2(s1, up2(d1.w), a67);
    }
}

// ---------------------------------------------------------------------------
// Deformable sampling. Block = 4 bucketed queries x 8 heads x 8 lanes.
// ~17.9 TB/s effective L2 on 64B gather segments — measured equilibrium
// (r7 sched_barrier and r8 asm-vmcnt pipelines did not beat it).
// ---------------------------------------------------------------------------
__global__ __launch_bounds__(256, 4) void sample_kernel(
    const float* __restrict__ offs, const float* __restrict__ attnw,
    const float* __restrict__ refp, const unsigned short* __restrict__ ft,
    const int* __restrict__ order, unsigned short* __restrict__ aggb)
{
    __shared__ int4   sI[512];
    __shared__ float4 sW[512];
    int tid = threadIdx.x;
    int bid = blockIdx.x;
    int obid = (bid & 7) * 1360 + (bid >> 3);   // XCD-chunked swizzle

#pragma unroll
    for (int e = tid; e < 512; e += 256) {
        int qq = e >> 7, pc = e & 127;
        int bq = order[obid * 4 + qq];
        int h = pc >> 4, lvl = (pc >> 2) & 3;
        float2 off = *(const float2*)&offs[((size_t)bq * 128 + pc) * 2];
        float aw = attnw[(size_t)bq * 128 + pc];
        float2 rp = *(const float2*)&refp[(size_t)bq * 2];
        int b = (bq >= Qn) ? 1 : 0;
        int Wl = 128 >> lvl;
        int base = (lvl == 0) ? 0 : (lvl == 1) ? 16384 : (lvl == 2) ? 20480 : 21504;
        float x = (rp.x + 0.5f * off.x) * (float)(Wl - 1);
        float y = (rp.y + 0.5f * off.y) * (float)(Wl - 1);
        float xf = floorf(x), yf = floorf(y);
        int x0 = (int)xf, y0 = (int)yf;
        float wx1 = x - xf, wx0 = 1.0f - wx1;
        float wy1 = y - yf, wy0 = 1.0f - wy1;
        float vx0 = (x0 >= 0 && x0 < Wl) ? 1.0f : 0.0f;
        float vx1 = (x0 + 1 >= 0 && x0 + 1 < Wl) ? 1.0f : 0.0f;
        float vy0 = (y0 >= 0 && y0 < Wl) ? 1.0f : 0.0f;
        float vy1 = (y0 + 1 >= 0 && y0 + 1 < Wl) ? 1.0f : 0.0f;
        int xc0 = min(max(x0, 0), Wl - 1), xc1 = min(max(x0 + 1, 0), Wl - 1);
        int yc0 = min(max(y0, 0), Wl - 1), yc1 = min(max(y0 + 1, 0), Wl - 1);
        int slab = (b * 8 + h) * HWSUM + base;
        int es = e ^ h;                          // LDS bank swizzle
        sI[es] = make_int4((slab + yc0 * Wl + xc0) * 64,     // byte offsets
                           (slab + yc1 * Wl + xc0) * 64,
                           (xc1 - xc0) * 64, 0);
        sW[es] = make_float4(wx0 * wy0 * vx0 * vy0 * aw,
                             wx1 * wy0 * vx1 * vy0 * aw,
                             wx0 * wy1 * vx0 * vy1 * aw,
                             wx1 * wy1 * vx1 * vy1 * aw);
    }
    __syncthreads();

    int qq = tid >> 6;
    int h = (tid >> 3) & 7;
    int l = tid & 7;
    int cl2 = (l & 3) * 16;
    bool hiLane = (l & 4) != 0;
    const char* fb = (const char*)ft;
    f32x2 a01 = {0.f, 0.f}, a23 = {0.f, 0.f}, a45 = {0.f, 0.f}, a67 = {0.f, 0.f};
    int ebase = qq * 128 + h * 16;

    uint4 dA[8]; float2 wA[4];
    uint4 dB[8]; float2 wB[4];

    issue4(sI, sW, fb, ebase, 0, h, cl2, hiLane, dA, wA);
    issue4(sI, sW, fb, ebase, 4, h, cl2, hiLane, dB, wB);
    consume4(dA, wA, a01, a23, a45, a67);
    issue4(sI, sW, fb, ebase, 8, h, cl2, hiLane, dA, wA);
    consume4(dB, wB, a01, a23, a45, a67);
    issue4(sI, sW, fb, ebase, 12, h, cl2, hiLane, dB, wB);
    consume4(dA, wA, a01, a23, a45, a67);
    consume4(dB, wB, a01, a23, a45, a67);

    float av[8] = {a01.x, a01.y, a23.x, a23.y, a45.x, a45.y, a67.x, a67.y};
#pragma unroll
    for (int k = 0; k < 8; ++k) av[k] += __shfl_xor(av[k], 4);
    if (!hiLane) {
        int bq = order[obid * 4 + qq];
        uint4 o;
        o.x = (unsigned)f2bf(av[0]) | ((unsigned)f2bf(av[1]) << 16);
        o.y = (unsigned)f2bf(av[2]) | ((unsigned)f2bf(av[3]) << 16);
        o.z = (unsigned)f2bf(av[4]) | ((unsigned)f2bf(av[5]) << 16);
        o.w = (unsigned)f2bf(av[6]) | ((unsigned)f2bf(av[7]) << 16);
        *(uint4*)&aggb[(size_t)bq * 256 + h * 32 + (l & 3) * 8] = o;
    }
}

// ---------------------------------------------------------------------------
// bf16 MFMA GEMM for the output projection: C = A[M,256] @ Bt[N,256]^T + bias.
// ---------------------------------------------------------------------------
__global__ __launch_bounds__(256) void mfma_gemm(
    const unsigned short* __restrict__ Abf, const unsigned short* __restrict__ Bt,
    const float* __restrict__ bias, float* __restrict__ C, int N)
{
    __shared__ unsigned short As[128 * 32];
    __shared__ unsigned short Bs[128 * 32];
    int tid = threadIdx.x;
    int m0 = blockIdx.x * 128, n0 = blockIdx.y * 128;
    int wave = tid >> 6, lane = tid & 63;
    int wr = wave >> 1, wc = wave & 1;
    int lr = lane & 15, kb = (lane >> 4) * 8;
    int arow = tid >> 2, aseg = (tid & 3) * 8;
    const unsigned short* Ag = Abf + (size_t)(m0 + arow) * 256 + aseg;
    const unsigned short* Bg = Bt + (size_t)(n0 + arow) * 256 + aseg;
    f32x4 acc[4][4] = {};
    for (int kt = 0; kt < 256; kt += 32) {
        async16(Ag + kt,            &As[tid * 8]);
        async16(Ag + 64 * 256 + kt, &As[tid * 8 + 2048]);
        async16(Bg + kt,            &Bs[tid * 8]);
        async16(Bg + 64 * 256 + kt, &Bs[tid * 8 + 2048]);
        __syncthreads();
        bf16x8 af[4], bfr[4];
#pragma unroll
        for (int i = 0; i < 4; ++i) {
            af[i]  = *(const bf16x8*)&As[(wr * 64 + i * 16 + lr) * 32 + kb];
            bfr[i] = *(const bf16x8*)&Bs[(wc * 64 + i * 16 + lr) * 32 + kb];
        }
#pragma unroll
        for (int i = 0; i < 4; ++i)
#pragma unroll
            for (int j = 0; j < 4; ++j)
                acc[i][j] = __builtin_amdgcn_mfma_f32_16x16x32_bf16(
                    af[i], bfr[j], acc[i][j], 0, 0, 0);
        __syncthreads();
    }
    int crow = (lane >> 4) * 4;
#pragma unroll
    for (int j = 0; j < 4; ++j) {
        int gcol = n0 + wc * 64 + j * 16 + lr;
        float bv = bias[gcol];
#pragma unroll
        for (int i = 0; i < 4; ++i) {
            int grow = m0 + wr * 64 + i * 16 + crow;
#pragma unroll
            for (int r = 0; r < 4; ++r)
                C[(size_t)(grow + r) * N + gcol] = acc[i][j][r] + bv;
        }
    }
}

// ---------------------------------------------------------------------------
extern "C" void kernel_launch(void* const* d_in, const int* in_sizes, int n_in,
                              void* d_out, int out_size, void* d_ws, size_t ws_size,
                              hipStream_t stream)
{
    const float* query  = (const float*)d_in[0];
    const float* f0     = (const float*)d_in[1];
    const float* f1     = (const float*)d_in[2];
    const float* f2     = (const float*)d_in[3];
    const float* f3     = (const float*)d_in[4];
    const float* refp   = (const float*)d_in[5];
    const float* W_off  = (const float*)d_in[6];
    const float* b_off  = (const float*)d_in[7];
    const float* W_attn = (const float*)d_in[8];
    const float* b_attn = (const float*)d_in[9];
    const float* W_out  = (const float*)d_in[10];
    const float* b_out  = (const float*)d_in[11];

    float* out      = (float*)d_out;                       // (B,Q,256)
    float* attn_out = out + (size_t)BQ * 256;              // (B,Q,8,4,4)

    // Workspace layout (bytes):
    char* w = (char*)d_ws;
    float* offs          = (float*)(w + 0);                 // 44,564,480
    unsigned short* ft   = (unsigned short*)(w + 44564480); // 22,282,240
    unsigned short* aggb = (unsigned short*)(w + 66846720); // 22,282,240
    unsigned short* Wcat = (unsigned short*)(w + 89128960); // 196,608 [384][256] hi
    unsigned short* Wlo  = (unsigned short*)(w + 89325568); // 131,072 [256][256] lo
    unsigned short* wout = (unsigned short*)(w + 89456640); // 131,072
    int* hist            = (int*)(w + 89587712);            //   2,048
    int* cnt             = (int*)(w + 89589760);            //   2,048
    int* order           = (int*)(w + 89591808);            // 174,080

    // zero hist + cnt (contiguous 4KB), graph-capturable
    hipMemsetAsync(hist, 0, 4096, stream);

    // transpose + weight split + histogram (one launch)
    transpose_prep_kernel<<<dim3(11040), 256, 0, stream>>>(
        f0, f1, f2, f3, refp, hist, ft,
        W_off, W_attn, W_out, Wcat, Wlo, wout);

    // offsets + attn + softmax, with scatter piggybacked (blocks 680..849)
    qproj_kernel<<<dim3(850), 256, 0, stream>>>(
        query, Wcat, Wlo, b_off, b_attn, offs, attn_out,
        refp, hist, cnt, order);

    // sampling + aggregation -> agg bf16
    sample_kernel<<<dim3(10880), 256, 0, stream>>>(
        offs, attn_out, refp, ft, order, aggb);

    // out = agg @ W_out + b_out
    mfma_gemm<<<dim3(340, 2), 256, 0, stream>>>(aggb, wout, b_out, out, 256);
}